// Round 11
// baseline (66.060 us; speedup 1.0000x reference)
//
#include <hip/hip_runtime.h>
#include <math.h>

#define NATOMS 32
#define NMOL   64
#define RCRf 5.2f
#define RCAf 3.5f

// Molecule-centric: 512 blocks x 512 threads. Block = (mol = blk>>3, centers
// i0..i0+3 with i0=(blk&7)*4). The 32x32 pair table (dv,d,fca,fcr) is built
// ONCE per block by ALL 8 waves (2 entries/thread) and shared by 4 centers.
// Angular: thread tid<496 decodes its (j<k) pair ONCE, loops 4 centers;
//   valid triples compute factorized f1[8]/f2f[4] and scatter 32 consecutive
//   LDS atomicAdds (32 consecutive dwords -> all 32 banks).
// Radial: thread=(j,shift), loops 4 centers: 1 expf + 1 atomic each.
// Epilogue: contiguous 1536-float coalesced writeback. 3 barriers, no
// single-wave phases, no sorting machinery.
__global__ __launch_bounds__(512) void aev_kernel(const int* __restrict__ species,
                                                  const float* __restrict__ coords,
                                                  float* __restrict__ out) {
    const int blk = blockIdx.x;
    const int mol = blk >> 3;
    const int i0  = (blk & 7) << 2;
    const int tid = threadIdx.x;

    __shared__ float  s_crd[NATOMS*3];
    __shared__ int    s_sp[NATOMS];
    __shared__ float4 s_pair[NATOMS][NATOMS];   // row a = center: dx,dy,dz,d (b rel a)
    __shared__ float2 s_fc[NATOMS][NATOMS];     // fca, fcr
    __shared__ float  s_acc[4][384];            // 4 centers x (64 radial + 320 angular)

    // ---------- phase 0: loads + acc zero ----------
    if (tid < NATOMS*3) s_crd[tid] = coords[(size_t)mol*NATOMS*3 + tid];
    if (tid < NATOMS)   s_sp[tid]  = species[mol*NATOMS + tid];
    #pragma unroll
    for (int f = tid; f < 4*384; f += 512) ((float*)s_acc)[f] = 0.f;
    __syncthreads();

    // ---------- phase 1: 32x32 pair table, 2 entries/thread ----------
    #pragma unroll
    for (int rep = 0; rep < 2; ++rep) {
        int e = tid + rep*512;
        int a = e >> 5, b = e & 31;
        float dx = s_crd[b*3+0] - s_crd[a*3+0];   // diff[a][b] = coord[b]-coord[a]
        float dy = s_crd[b*3+1] - s_crd[a*3+1];
        float dz = s_crd[b*3+2] - s_crd[a*3+2];
        float d2 = dx*dx + dy*dy + dz*dz;
        float d  = sqrtf(d2 > 0.f ? d2 : 1.f);    // ref's where(d2>0,d2,1) guard
        bool self = (a == b);
        float fca = (!self && d <= RCAf) ? (0.5f*__cosf(((float)M_PI/RCAf)*d) + 0.5f) : 0.f;
        float fcr = (!self && d <= RCRf) ? (0.5f*__cosf(((float)M_PI/RCRf)*d) + 0.5f) : 0.f;
        s_pair[a][b] = make_float4(dx, dy, dz, d);
        s_fc[a][b]   = make_float2(fca, fcr);
    }
    __syncthreads();

    // ---------- phase 2a: angular triples ----------
    const float CZ[8] = { 0.98078528f,  0.83146961f,  0.55557023f,  0.19509032f,
                         -0.19509032f, -0.55557023f, -0.83146961f, -0.98078528f};
    const float SZ[8] = { 0.19509032f,  0.55557023f,  0.83146961f,  0.98078528f,
                          0.98078528f,  0.83146961f,  0.55557023f,  0.19509032f};
    const float SHA[4] = {0.9f, 1.55f, 2.2f, 2.85f};

    if (tid < 496) {
        // closed-form triangular decode (R5-proven): off(j) = j*(63-j)/2
        float t = sqrtf((float)(3969 - 8*tid));
        int j = (int)((63.0f - t) * 0.5f);
        if (j*(63-j)/2 > tid) --j;                // float-rounding fixups
        if ((j+1)*(62-j)/2 <= tid) ++j;
        int k = tid - j*(63-j)/2 + j + 1;
        int sj = s_sp[j], sk = s_sp[k];
        int lo = min(sj, sk), hi = max(sj, sk);
        int px = ((lo*(9-lo)) >> 1) + (hi - lo);  // triu pair index, S=4

        #pragma unroll
        for (int cen = 0; cen < 4; ++cen) {
            int i = i0 + cen;
            float fc2 = 2.f * s_fc[i][j].x * s_fc[i][k].x;
            if (fc2 > 0.f) {                       // both in RCA, both != i
                float4 aj = s_pair[i][j], ak = s_pair[i][k];
                float dot = aj.x*ak.x + aj.y*ak.y + aj.z*ak.z;
                float c = 0.95f * dot * __builtin_amdgcn_rcpf(aj.w * ak.w);
                c = fminf(0.95f, fmaxf(-0.95f, c));
                float s = sqrtf(1.f - c*c);        // sin(acos(c)), theta in [0,pi]
                float dmean = 0.5f * (aj.w + ak.w);
                float f1z[8], f2f[4];
                #pragma unroll
                for (int z = 0; z < 8; ++z) {
                    float x = 0.5f + 0.5f*(c*CZ[z] + s*SZ[z]);  // (1+cos(th-sz))/2
                    float q = x*x; q *= q; q *= q; q *= q; q *= q;  // ^32
                    f1z[z] = q;
                }
                #pragma unroll
                for (int a = 0; a < 4; ++a) {
                    float dm = dmean - SHA[a];
                    f2f[a] = __expf(-8.f*dm*dm) * fc2;
                }
                float* accp = &s_acc[cen][64 + px*32];
                #pragma unroll
                for (int a = 0; a < 4; ++a)
                    #pragma unroll
                    for (int z = 0; z < 8; ++z)
                        atomicAdd(&accp[a*8 + z], f2f[a]*f1z[z]);
            }
        }
    }

    // ---------- phase 2b: radial, thread = (j, shift) ----------
    {
        int j = tid >> 4, r = tid & 15;            // 32 x 16 = 512 exactly
        float shr = 0.9f + 0.26875f * (float)r;    // SHF_R
        int target = s_sp[j]*16 + r;
        #pragma unroll
        for (int cen = 0; cen < 4; ++cen) {
            int i = i0 + cen;
            float2 fc = s_fc[i][j];                // fc.y==0 encodes mask (j==i, d>RCR)
            if (fc.y > 0.f) {
                float dm = s_pair[i][j].w - shr;
                atomicAdd(&s_acc[cen][target], 0.25f * __expf(-16.f*dm*dm) * fc.y);
            }
        }
    }
    __syncthreads();

    // ---------- epilogue: contiguous coalesced writeback ----------
    float* ob = out + NMOL*NATOMS + (size_t)(mol*NATOMS + i0) * 384;
    #pragma unroll
    for (int f = tid; f < 4*384; f += 512) ob[f] = ((float*)s_acc)[f];
    if (tid < 4) out[mol*NATOMS + i0 + tid] = (float)s_sp[i0 + tid];
}

extern "C" void kernel_launch(void* const* d_in, const int* in_sizes, int n_in,
                              void* d_out, int out_size, void* d_ws, size_t ws_size,
                              hipStream_t stream) {
    const int*   species = (const int*)d_in[0];
    const float* coords  = (const float*)d_in[1];
    float*       out     = (float*)d_out;
    aev_kernel<<<NMOL*8, 512, 0, stream>>>(species, coords, out);
}

// Round 12
// 16.051 us; speedup vs baseline: 4.1157x; 4.1157x over previous
//
#include <hip/hip_runtime.h>
#include <math.h>

#define NATOMS 32
#define NMOL   64
#define MAXP   466     // >= C(31,2)=465
#define RCRf 5.2f
#define RCAf 3.5f

// One block per (molecule n, center atom i). 512 threads (8 waves), 3 barriers.
// A (wave 0 lanes 0..31): atom setup; ballot-compacted RCA neighbor list.
// B (tid<cnt, ALWAYS single pass since cnt<=465<512): decode pair in compacted
//    space, build factorized record {f1[0..7], f2f[0..3]} in REGISTERS,
//    histogram px via LDS atomic.
// C (tid<cnt): slot = in-register prefix(s_cnt[0..px)) + atomicAdd rank;
//    3x ds_write_b128. No serial scan phase, no extra barrier.
// E: tid<320 owns angular feature (b=tid>>5, a, z), scans only bucket b
//    (2 LDS reads + fma per record, register acc). tid 320..383: radial.
__global__ __launch_bounds__(512) void aev_kernel(const int* __restrict__ species,
                                                  const float* __restrict__ coords,
                                                  float* __restrict__ out) {
    const int bid = blockIdx.x;
    const int n = bid >> 5;
    const int i = bid & 31;
    const int tid = threadIdx.x;

    __shared__ float4 s_atom[NATOMS];            // dx, dy, dz, d
    __shared__ float2 s_dfr[NATOMS];             // d, fcr (radial)
    __shared__ float  s_fca[NATOMS];
    __shared__ int    s_sp[NATOMS];
    __shared__ int    s_nbr[NATOMS];
    __shared__ int    s_nn;
    __shared__ __align__(16) float s_rec[MAXP*12];   // f1[0..7], f2f[0..3]
    __shared__ int    s_cnt[10], s_rank[10];

    // ---------- phase A ----------
    if (tid < 10) { s_cnt[tid] = 0; s_rank[tid] = 0; }
    if (tid < 64) {
        float fca_v = 0.f;
        if (tid < NATOMS) {
            const float* cb = coords + (size_t)n*NATOMS*3;
            float dx = cb[tid*3+0] - cb[i*3+0];
            float dy = cb[tid*3+1] - cb[i*3+1];
            float dz = cb[tid*3+2] - cb[i*3+2];
            float d2 = dx*dx + dy*dy + dz*dz;
            float d  = sqrtf(d2 > 0.f ? d2 : 1.f);   // ref's where(d2>0,d2,1) guard
            bool self = (tid == i);
            float fr = (!self && d <= RCRf) ? (0.5f*__cosf(((float)M_PI/RCRf)*d) + 0.5f) : 0.f;
            fca_v    = (!self && d <= RCAf) ? (0.5f*__cosf(((float)M_PI/RCAf)*d) + 0.5f) : 0.f;
            s_atom[tid] = make_float4(dx, dy, dz, d);
            s_dfr[tid]  = make_float2(d, fr);
            s_fca[tid]  = fca_v;
            s_sp[tid]   = species[n*NATOMS + tid];
        }
        unsigned long long m = __ballot(fca_v > 0.f);  // full-wave-active context
        if (fca_v > 0.f) s_nbr[__popcll(m & ((1ull << tid) - 1ull))] = tid;
        if (tid == 0) s_nn = (int)__popcll(m);
    }
    __syncthreads();                                   // barrier 1

    const int nn  = s_nn;
    const int cnt = (nn*(nn-1)) >> 1;                  // <= 465 < 512: single pass
    const int M   = 2*nn - 1;

    const float CZ[8] = { 0.98078528f,  0.83146961f,  0.55557023f,  0.19509032f,
                         -0.19509032f, -0.55557023f, -0.83146961f, -0.98078528f};
    const float SZ[8] = { 0.19509032f,  0.55557023f,  0.83146961f,  0.98078528f,
                          0.98078528f,  0.83146961f,  0.55557023f,  0.19509032f};
    const float SHA[4] = {0.9f, 1.55f, 2.2f, 2.85f};

    // ---------- phase B: record build in registers + histogram ----------
    int px = -1;
    float4 v0, v1, v2;
    if (tid < cnt) {
        float t = sqrtf((float)(M*M - 8*tid));
        int jj = (int)(((float)M - t) * 0.5f);
        jj = max(0, min(jj, nn-2));
        while (jj*(2*nn-jj-1)/2 > tid) --jj;           // <=2 fixup steps
        while ((jj+1)*(2*nn-jj-2)/2 <= tid) ++jj;
        int kk = tid - jj*(2*nn-jj-1)/2 + jj + 1;
        int j = s_nbr[jj], k = s_nbr[kk];
        float4 aj = s_atom[j], ak = s_atom[k];
        float fc2 = 2.f * s_fca[j] * s_fca[k];
        float dot = aj.x*ak.x + aj.y*ak.y + aj.z*ak.z;
        float c = 0.95f * dot * __builtin_amdgcn_rcpf(aj.w * ak.w);
        c = fminf(0.95f, fmaxf(-0.95f, c));
        float s = sqrtf(1.f - c*c);                    // sin(acos(c))
        float dmean = 0.5f * (aj.w + ak.w);
        int sj = s_sp[j], sk = s_sp[k];
        int lo = min(sj, sk), hi = max(sj, sk);
        px = ((lo*(9-lo)) >> 1) + (hi - lo);           // triu pair index, S=4
        v0.x = 0.5f + 0.5f*(c*CZ[0] + s*SZ[0]);
        v0.y = 0.5f + 0.5f*(c*CZ[1] + s*SZ[1]);
        v0.z = 0.5f + 0.5f*(c*CZ[2] + s*SZ[2]);
        v0.w = 0.5f + 0.5f*(c*CZ[3] + s*SZ[3]);
        v1.x = 0.5f + 0.5f*(c*CZ[4] + s*SZ[4]);
        v1.y = 0.5f + 0.5f*(c*CZ[5] + s*SZ[5]);
        v1.z = 0.5f + 0.5f*(c*CZ[6] + s*SZ[6]);
        v1.w = 0.5f + 0.5f*(c*CZ[7] + s*SZ[7]);
        #define POW32(q) { q = q*q; q = q*q; q = q*q; q = q*q; q = q*q; }
        POW32(v0.x) POW32(v0.y) POW32(v0.z) POW32(v0.w)
        POW32(v1.x) POW32(v1.y) POW32(v1.z) POW32(v1.w)
        #undef POW32
        float dm0 = dmean - SHA[0], dm1 = dmean - SHA[1];
        float dm2 = dmean - SHA[2], dm3 = dmean - SHA[3];
        v2.x = __expf(-8.f*dm0*dm0) * fc2;
        v2.y = __expf(-8.f*dm1*dm1) * fc2;
        v2.z = __expf(-8.f*dm2*dm2) * fc2;
        v2.w = __expf(-8.f*dm3*dm3) * fc2;
        atomicAdd(&s_cnt[px], 1);
    }
    __syncthreads();                                   // barrier 2

    // counts complete: every thread reads them (broadcast) for prefix math
    int c0 = s_cnt[0], c1 = s_cnt[1], c2 = s_cnt[2], c3 = s_cnt[3], c4 = s_cnt[4];
    int c5 = s_cnt[5], c6 = s_cnt[6], c7 = s_cnt[7], c8 = s_cnt[8], c9 = s_cnt[9];

    // ---------- phase C: slot = prefix + rank; write record ----------
    if (px >= 0) {
        int base = 0;
        base += (px > 0) ? c0 : 0;  base += (px > 1) ? c1 : 0;
        base += (px > 2) ? c2 : 0;  base += (px > 3) ? c3 : 0;
        base += (px > 4) ? c4 : 0;  base += (px > 5) ? c5 : 0;
        base += (px > 6) ? c6 : 0;  base += (px > 7) ? c7 : 0;
        base += (px > 8) ? c8 : 0;
        int slot = base + atomicAdd(&s_rank[px], 1);
        float* r = &s_rec[slot*12];
        *(float4*)(r+0) = v0;
        *(float4*)(r+4) = v1;
        *(float4*)(r+8) = v2;
    }
    __syncthreads();                                   // barrier 3

    // ---------- phase E ----------
    float* oa = out + NMOL*NATOMS + (size_t)bid * 384;

    if (tid < 320) {
        const int b = tid >> 5;
        const int a = (tid >> 3) & 3;
        const int z = tid & 7;
        int base = 0;
        base += (b > 0) ? c0 : 0;  base += (b > 1) ? c1 : 0;
        base += (b > 2) ? c2 : 0;  base += (b > 3) ? c3 : 0;
        base += (b > 4) ? c4 : 0;  base += (b > 5) ? c5 : 0;
        base += (b > 6) ? c6 : 0;  base += (b > 7) ? c7 : 0;
        base += (b > 8) ? c8 : 0;
        int bc = b==0?c0 : b==1?c1 : b==2?c2 : b==3?c3 : b==4?c4
               : b==5?c5 : b==6?c6 : b==7?c7 : b==8?c8 : c9;
        float acc = 0.f;
        #pragma unroll 4
        for (int q = base; q < base + bc; ++q)
            acc += s_rec[q*12 + z] * s_rec[q*12 + 8 + a];
        oa[64 + tid] = acc;
        if (tid == 0) out[bid] = (float)s_sp[i];       // output 0: species
    } else if (tid < 384) {
        const int f  = tid - 320;
        const int rs = f >> 4;
        const float shr = 0.9f + 0.26875f * (float)(f & 15);   // SHF_R
        float racc = 0.f;
        #pragma unroll 8
        for (int j = 0; j < NATOMS; ++j) {
            float2 dfr = s_dfr[j];                     // fr==0 encodes mask
            float dmr = dfr.x - shr;
            racc += (s_sp[j] == rs) ? 0.25f * __expf(-16.f*dmr*dmr) * dfr.y : 0.f;
        }
        oa[f] = racc;
    }
}

extern "C" void kernel_launch(void* const* d_in, const int* in_sizes, int n_in,
                              void* d_out, int out_size, void* d_ws, size_t ws_size,
                              hipStream_t stream) {
    const int*   species = (const int*)d_in[0];
    const float* coords  = (const float*)d_in[1];
    float*       out     = (float*)d_out;
    aev_kernel<<<NMOL * NATOMS, 512, 0, stream>>>(species, coords, out);
}